// Round 5
// baseline (477.811 us; speedup 1.0000x reference)
//
#include <hip/hip_runtime.h>

// LocallyConnected3DFlipout:
//   out[b,p,f] = sum_k patch[b,p,k]*loc[p,k,f]
//              + sign_out[b,p,f]*sum_k (x*sign_in)patch[b,p,k]*(softplus(rho)*eps)[p,k,f]
//              + bias[f]
// patch k = c*27 + (kd*9+kh*3+kw)  (channel slowest, spatial row-major fastest).
//
// R5: single kernel, software-pipelined weight staging.
// R3's 98.6 us decomposed as: whole-device stage burst (~18 us) -> barrier ->
// compute with HBM idle (~30 us) -> 92-block tail (grid 1372 ~= one residency
// generation of 5 blocks/CU). Fix: split K into 3 kd-plane chunks of 36,
// double-buffer the LDS slab, and issue chunk kd+1's global loads before
// computing chunk kd so the 114 MB weight stream overlaps the FMAs.
// R4's two-kernel split regressed (weight tile re-fetched ~3x across XCDs,
// +pack kernel time); reverted.
//
// Mapping (from R3, verified): lanes p-fastest (16 p x 4 bh per wave), each
// thread 2 batches (bh, bh+16). bf16-packed weights: absmax 0.0156 vs 0.0578.
// LDS chunk buffer [pl][c*9+j], pl-stride 37 uint4 (148 dwords == 20 mod 32
// -> 16 pl map to 8 bank-quads x2 = 2-way, free per m136).

constexpr int Bn   = 32;
constexpr int Dn   = 30;
constexpr int Cn   = 4;
constexpr int ODn  = 28;
constexpr int Pn   = ODn * ODn * ODn;   // 21952
constexpr int Tt   = 27;
constexpr int Kn   = Tt * Cn;           // 108
constexpr int PPB  = 16;                // positions per block
constexpr int THREADS = 256;
constexpr int CHK  = 36;                // k per chunk (one kd-plane: 4c x 9 taps)
constexpr int NITEM = PPB * CHK;        // 576 staged uint4 per chunk
constexpr int WST  = 37;                // uint4 stride per p in LDS buffer
constexpr int BUFSZ = PPB * WST;        // 592 uint4 = 9472 B per buffer

__device__ __forceinline__ unsigned bf16rne(float f) {
    unsigned u = __float_as_uint(f);
    return (u + 0x7fffu + ((u >> 16) & 1u)) >> 16;
}
__device__ __forceinline__ float bflo(unsigned u) { return __uint_as_float(u << 16); }
__device__ __forceinline__ float bfhi(unsigned u) { return __uint_as_float(u & 0xffff0000u); }

__device__ __forceinline__ uint4 packw(float4 L, float4 R, float4 E) {
    float nx = (R.x > 15.f ? R.x : __logf(1.f + __expf(R.x))) * E.x;
    float ny = (R.y > 15.f ? R.y : __logf(1.f + __expf(R.y))) * E.y;
    float nz = (R.z > 15.f ? R.z : __logf(1.f + __expf(R.z))) * E.z;
    float nw = (R.w > 15.f ? R.w : __logf(1.f + __expf(R.w))) * E.w;
    uint4 pk;
    pk.x = bf16rne(L.x) | (bf16rne(L.y) << 16);
    pk.y = bf16rne(L.z) | (bf16rne(L.w) << 16);
    pk.z = bf16rne(nx)  | (bf16rne(ny) << 16);
    pk.w = bf16rne(nz)  | (bf16rne(nw) << 16);
    return pk;
}

__global__ __launch_bounds__(THREADS) void lc3d_flipout_kernel(
    const float* __restrict__ x,        // [B,30,30,30,4]
    const float* __restrict__ loc,      // [P,108,4]
    const float* __restrict__ rho,      // [P,108,4]
    const float* __restrict__ bias,     // [4]
    const float* __restrict__ eps,      // [P,108,4]
    const float* __restrict__ sgn_in,   // [B,30,30,30,4]
    const float* __restrict__ sgn_out,  // [B,P,4]
    float* __restrict__ out)            // [B,P,4]
{
    __shared__ uint4 wbuf[2][BUFSZ];

    const int tid    = threadIdx.x;
    const int p_base = blockIdx.x * PPB;

    const float4* loc4 = (const float4*)loc;
    const float4* rho4 = (const float4*)rho;
    const float4* eps4 = (const float4*)eps;

    // ---- Staged-item indices: g in [0,576): pl=g/36, c=(g%36)/9, j=g%9.
    //      src (float4, +kd*9 per chunk) = (p_base+pl)*108 + c*27 + j
    //      dst (uint4)                   = pl*37 + c*9 + j
    const int g0 = tid, g1 = tid + THREADS, g2 = tid + 2 * THREADS; // g2: tid<64
    int s0, d0, s1, d1, s2 = 0, d2 = 0;
    {
        int pl = g0 / CHK, r = g0 - pl * CHK, c = r / 9, j = r - c * 9;
        s0 = (p_base + pl) * Kn + c * Tt + j;  d0 = pl * WST + r;
        pl = g1 / CHK; r = g1 - pl * CHK; c = r / 9; j = r - c * 9;
        s1 = (p_base + pl) * Kn + c * Tt + j;  d1 = pl * WST + r;
        if (tid < 64) {
            pl = g2 / CHK; r = g2 - pl * CHK; c = r / 9; j = r - c * 9;
            s2 = (p_base + pl) * Kn + c * Tt + j;  d2 = pl * WST + r;
        }
    }

    // ---- Compute-side mapping (R3) ----
    const int pl = tid & 15;
    const int bh = tid >> 4;            // 0..15
    const int b0 = bh, b1 = bh + 16;
    const int p  = p_base + pl;
    const int od   = p / (ODn * ODn);
    const int prem = p - od * (ODn * ODn);
    const int oh   = prem / ODn;
    const int ow   = prem - oh * ODn;

    const float4* x4 = (const float4*)x;
    const float4* s4 = (const float4*)sgn_in;
    const size_t v0 = (((size_t)b0 * Dn + od) * Dn + oh) * Dn + ow;
    const size_t v1 = (((size_t)b1 * Dn + od) * Dn + oh) * Dn + ow;

    float a00=0.f,a01=0.f,a02=0.f,a03=0.f;   // mean acc, b0
    float a10=0.f,a11=0.f,a12=0.f,a13=0.f;   // mean acc, b1
    float n00=0.f,n01=0.f,n02=0.f,n03=0.f;   // noise acc, b0
    float n10=0.f,n11=0.f,n12=0.f,n13=0.f;   // noise acc, b1

    // ---- Prologue: stage chunk 0 into buffer 0 ----
    float4 L0 = loc4[s0], R0 = rho4[s0], E0 = eps4[s0];
    float4 L1 = loc4[s1], R1 = rho4[s1], E1 = eps4[s1];
    float4 L2, R2, E2;
    if (tid < 64) { L2 = loc4[s2]; R2 = rho4[s2]; E2 = eps4[s2]; }
    wbuf[0][d0] = packw(L0, R0, E0);
    wbuf[0][d1] = packw(L1, R1, E1);
    if (tid < 64) wbuf[0][d2] = packw(L2, R2, E2);
    __syncthreads();

#define CHAN(WV, xa_c, sa_c, xb_c, sb_c)                                     \
    {                                                                        \
        const float m0 = bflo(WV.x), m1 = bfhi(WV.x);                        \
        const float m2 = bflo(WV.y), m3 = bfhi(WV.y);                        \
        const float q0 = bflo(WV.z), q1 = bfhi(WV.z);                        \
        const float q2 = bflo(WV.w), q3 = bfhi(WV.w);                        \
        a00 = fmaf(xa_c, m0, a00); a01 = fmaf(xa_c, m1, a01);                \
        a02 = fmaf(xa_c, m2, a02); a03 = fmaf(xa_c, m3, a03);                \
        a10 = fmaf(xb_c, m0, a10); a11 = fmaf(xb_c, m1, a11);                \
        a12 = fmaf(xb_c, m2, a12); a13 = fmaf(xb_c, m3, a13);                \
        const float ya = (xa_c) * (sa_c);                                    \
        const float yb = (xb_c) * (sb_c);                                    \
        n00 = fmaf(ya, q0, n00); n01 = fmaf(ya, q1, n01);                    \
        n02 = fmaf(ya, q2, n02); n03 = fmaf(ya, q3, n03);                    \
        n10 = fmaf(yb, q0, n10); n11 = fmaf(yb, q1, n11);                    \
        n12 = fmaf(yb, q2, n12); n13 = fmaf(yb, q3, n13);                    \
    }

    #pragma unroll
    for (int kd = 0; kd < 3; ++kd) {
        // ---- Issue next chunk's global loads (overlap with compute below) ----
        if (kd < 2) {
            const int o = (kd + 1) * 9;
            L0 = loc4[s0 + o]; R0 = rho4[s0 + o]; E0 = eps4[s0 + o];
            L1 = loc4[s1 + o]; R1 = rho4[s1 + o]; E1 = eps4[s1 + o];
            if (tid < 64) { L2 = loc4[s2 + o]; R2 = rho4[s2 + o]; E2 = eps4[s2 + o]; }
        }

        // ---- Compute chunk kd from wbuf[kd&1] ----
        const uint4* wp = wbuf[kd & 1] + pl * WST;
        #pragma unroll
        for (int kh = 0; kh < 3; ++kh) {
            #pragma unroll
            for (int kw = 0; kw < 3; ++kw) {
                const int tl   = kh * 3 + kw;
                const int roff = (kd * Dn + kh) * Dn + kw;
                const float4 xa = x4[v0 + roff];
                const float4 sa = s4[v0 + roff];
                const float4 xb = x4[v1 + roff];
                const float4 sb = s4[v1 + roff];
                const uint4 w0 = wp[0 * 9 + tl];
                const uint4 w1 = wp[1 * 9 + tl];
                const uint4 w2 = wp[2 * 9 + tl];
                const uint4 w3 = wp[3 * 9 + tl];
                CHAN(w0, xa.x, sa.x, xb.x, sb.x);
                CHAN(w1, xa.y, sa.y, xb.y, sb.y);
                CHAN(w2, xa.z, sa.z, xb.z, sb.z);
                CHAN(w3, xa.w, sa.w, xb.w, sb.w);
            }
        }

        // ---- Pack + write next chunk into the other buffer ----
        if (kd < 2) {
            uint4* nb = wbuf[(kd + 1) & 1];
            nb[d0] = packw(L0, R0, E0);
            nb[d1] = packw(L1, R1, E1);
            if (tid < 64) nb[d2] = packw(L2, R2, E2);
            __syncthreads();
        }
    }
#undef CHAN

    // ---- Epilogue: coalesced (16 consecutive p per cluster) ----
    const float4 bi = *(const float4*)bias;
    const size_t ob0 = (size_t)b0 * Pn + p;
    const size_t ob1 = (size_t)b1 * Pn + p;
    const float4 so0 = ((const float4*)sgn_out)[ob0];
    const float4 so1 = ((const float4*)sgn_out)[ob1];
    float4 o0, o1;
    o0.x = fmaf(so0.x, n00, a00) + bi.x;
    o0.y = fmaf(so0.y, n01, a01) + bi.y;
    o0.z = fmaf(so0.z, n02, a02) + bi.z;
    o0.w = fmaf(so0.w, n03, a03) + bi.w;
    o1.x = fmaf(so1.x, n10, a10) + bi.x;
    o1.y = fmaf(so1.y, n11, a11) + bi.y;
    o1.z = fmaf(so1.z, n12, a12) + bi.z;
    o1.w = fmaf(so1.w, n13, a13) + bi.w;
    ((float4*)out)[ob0] = o0;
    ((float4*)out)[ob1] = o1;
}

extern "C" void kernel_launch(void* const* d_in, const int* in_sizes, int n_in,
                              void* d_out, int out_size, void* d_ws, size_t ws_size,
                              hipStream_t stream) {
    const float* x    = (const float*)d_in[0];
    const float* loc  = (const float*)d_in[1];
    const float* rho  = (const float*)d_in[2];
    const float* bias = (const float*)d_in[3];
    const float* eps  = (const float*)d_in[4];
    const float* si   = (const float*)d_in[5];
    const float* so   = (const float*)d_in[6];
    float* out = (float*)d_out;

    lc3d_flipout_kernel<<<dim3(Pn / PPB), dim3(THREADS), 0, stream>>>(
        x, loc, rho, bias, eps, si, so, out);
}